// Round 8
// baseline (504.457 us; speedup 1.0000x reference)
//
#include <hip/hip_runtime.h>
#include <stdint.h>

// SuperpointGenerator: per-batch voxel id -> count -> top-256 by (count desc, id asc)
// -> labels 0..255 (else -1); if U<=256, label = dense rank by ascending id.
//
// Hash table entry (64-bit): (u << 32) | low32, where u = id ^ 0x80000000 (never 0).
//   During build:  low32 = count (<= 2^18 = 0x40000).
//   After select:  winners' low32 = ~rank (>= 0xFFFFFF00). Decode: low >= 0xFFF00000.
//
// k_build: persistent blocks read HW_REG_XCC_ID and only process batches
// b = xcd, xcd+8 (per-XCD work queue). All table RMWs for batch b therefore
// come from one XCD, so they can use WORKGROUP-scope atomics, which execute
// in the local L2 (no sc1 memory-side round trip). R7 measured device-scope
// atomics cost one 64B line round trip each (267 MB for 4.19M points).
// Cross-kernel visibility: kernel-completion agent-scope release writes back L2.
//
// Other kernels keep the bid%8 swizzle purely as an L2-locality heuristic.
//
// Top-256 selection: grid-parallel MSB-first radix select (5 passes x 10-bit
// digits over the 50-bit key), one hist+pick kernel pair per pass.

namespace {
constexpr int B_ = 16;
constexpr int N_ = 262144;          // 2^18 points per batch
constexpr int LOGN_ = 18;
constexpr int K_ = 256;
constexpr int LOGC_ = 17;
constexpr int C_ = 1 << LOGC_;      // hash table slots per batch (U ~= 43K measured)
constexpr unsigned CMASK_ = C_ - 1;
constexpr unsigned GRANS_PER_XCD_ = 64;   // 2 batches x 32 granules of 8192 points
typedef unsigned long long ull;
}

__device__ __forceinline__ unsigned hash_id(int id) {
    unsigned h = (unsigned)id * 2654435761u;   // Knuth multiplicative
    return h >> (32 - LOGC_);                  // upper bits -> [0, C)
}

// bid -> (batch, chunk): batch = (bid&7) + 8*((bid>>3)&1)  => batch % 8 == bid % 8
__device__ __forceinline__ void swz(int bid, int& b, int& chunk) {
    b = (bid & 7) + (((bid >> 3) & 1) << 3);
    chunk = bid >> 4;
}

__global__ void __launch_bounds__(1024)
k_init0(ull* __restrict__ pfx, unsigned* __restrict__ ghist,
        unsigned* __restrict__ csize, unsigned* __restrict__ gwc,
        unsigned* __restrict__ remg, unsigned* __restrict__ wctr) {
    int b = blockIdx.x, t = threadIdx.x;       // grid == 16 x 1024
    ghist[b * 1024 + t] = 0u;
    if (t == 0) { csize[b] = 0u; gwc[b] = 0u; pfx[b] = 0ull; remg[b] = (unsigned)K_; }
    if (b == 0 && t < 128) wctr[t] = 0u;
}

__global__ void __launch_bounds__(256)
k_build(const float* __restrict__ coords, ull* __restrict__ tab,
        int* __restrict__ pslot, unsigned* __restrict__ wctr) {
    unsigned xcd;
    asm volatile("s_getreg_b32 %0, hwreg(HW_REG_XCC_ID)" : "=s"(xcd));
    xcd &= 7u;                                   // this block's XCD (block-uniform)
    __shared__ unsigned sg;
    for (;;) {
        __syncthreads();                         // protect sg from previous iter
        if (threadIdx.x == 0) sg = atomicAdd(&wctr[xcd << 4], 1u);  // device-scope: ok
        __syncthreads();
        unsigned g = sg;                         // block-uniform granule index
        if (g >= GRANS_PER_XCD_) break;
        int b = (int)xcd + (int)((g & 1u) << 3); // batches xcd, xcd+8 alternate
        int pbase = (int)(g >> 1) << 13;         // granule = 8192 points
        ull* t = tab + (size_t)b * C_;
        for (int r = 0; r < 32; ++r) {           // 32 coalesced sweeps x 256 threads
            int p = pbase + (r << 8) + (int)threadIdx.x;
            size_t i = ((size_t)b << LOGN_) + (size_t)p;
            const float* c = coords + i * 3;
            // Must match jnp.floor(c / 0.2f) bit-exactly: IEEE fp32 division.
            float cx = __builtin_nontemporal_load(c + 0);
            float cy = __builtin_nontemporal_load(c + 1);
            float cz = __builtin_nontemporal_load(c + 2);
            int vx = (int)floorf(cx / 0.2f);
            int vy = (int)floorf(cy / 0.2f);
            int vz = (int)floorf(cz / 0.2f);
            int id = vx * 10000 + vy * 100 + vz;
            unsigned u = (unsigned)id ^ 0x80000000u;
            unsigned s = hash_id(id);
            for (;;) {
                ull cur = t[s];      // plain load: stale-safe (slot id monotone 0->u)
                if (cur == 0ull) {
                    ull expected = 0ull;
                    if (__hip_atomic_compare_exchange_strong(
                            &t[s], &expected, ((ull)u << 32) | 1ull,
                            __ATOMIC_RELAXED, __ATOMIC_RELAXED,
                            __HIP_MEMORY_SCOPE_WORKGROUP))
                        break;                   // inserted
                    cur = expected;
                }
                if ((unsigned)(cur >> 32) == u) {
                    __hip_atomic_fetch_add(&t[s], 1ull, __ATOMIC_RELAXED,
                                           __HIP_MEMORY_SCOPE_WORKGROUP);
                    break;
                }
                s = (s + 1) & CMASK_;            // collision: linear probe
            }
            __builtin_nontemporal_store((int)s, &pslot[i]);
        }
    }
}

// Compact occupied slots into per-batch key arrays (block-aggregated append).
__global__ void __launch_bounds__(1024)
k_compact(const ull* __restrict__ tab, ull* __restrict__ ckeys,
          unsigned* __restrict__ csize) {
    int b, chunk;
    swz(blockIdx.x, b, chunk);                       // grid == B_*C_/1024
    int i = b * C_ + chunk * 1024 + threadIdx.x;
    ull e = __builtin_nontemporal_load(&tab[i]);     // sequential scan, no reuse here
    bool valid = (e != 0ull);
    // priority key: (count desc, id asc) -> larger key = higher priority
    ull key = ((ull)(unsigned)e << 32) | (ull)(~(unsigned)(e >> 32));

    unsigned long long mask = __ballot(valid);
    int lane = threadIdx.x & 63;
    int wave = threadIdx.x >> 6;                     // 0..15

    __shared__ unsigned woff[16];
    __shared__ unsigned blockbase;
    if (lane == 0) woff[wave] = (unsigned)__popcll(mask);
    __syncthreads();
    if (threadIdx.x == 0) {
        unsigned tot = 0;
        for (int w2 = 0; w2 < 16; ++w2) { unsigned c = woff[w2]; woff[w2] = tot; tot += c; }
        blockbase = (tot != 0u) ? atomicAdd(&csize[b], tot) : 0u;
    }
    __syncthreads();
    if (valid) {
        unsigned pos = blockbase + woff[wave]
                     + (unsigned)__popcll(mask & ((1ull << lane) - 1ull));
        ckeys[(size_t)b * C_ + pos] = key;           // re-read 5x by k_hist: keep cached
    }
}

// One radix pass histogram: keys matching current prefix contribute their 10-bit digit.
__global__ void __launch_bounds__(256)
k_hist(const unsigned* __restrict__ csize, const ull* __restrict__ ckeys,
       const ull* __restrict__ pfx, unsigned* __restrict__ ghist, int sh) {
    int b, chunk;
    swz(blockIdx.x, b, chunk);                       // grid == 128 -> chunk 0..7
    int U = (int)csize[b];
    if (U <= K_) return;
    ull prefix = pfx[b];
    ull hi = ~0ull << (sh + 10);                     // bits above current digit
    __shared__ unsigned lh[1024];
    for (int d = threadIdx.x; d < 1024; d += 256) lh[d] = 0u;
    __syncthreads();
    const ull* keys = ckeys + (size_t)b * C_;
    for (int i = chunk * 256 + threadIdx.x; i < U; i += 2048) {
        ull k = keys[i];
        if ((k & hi) == prefix)
            atomicAdd(&lh[(unsigned)(k >> sh) & 1023u], 1u);
    }
    __syncthreads();
    for (int d = threadIdx.x; d < 1024; d += 256) {
        unsigned c = lh[d];
        if (c) atomicAdd(&ghist[b * 1024 + d], c);
    }
}

// Pick the digit bin containing the rem-th largest; update prefix/rem; re-zero ghist.
__global__ void __launch_bounds__(1024)
k_pick(const unsigned* __restrict__ csize, unsigned* __restrict__ ghist,
       ull* __restrict__ pfx, unsigned* __restrict__ remg, int sh) {
    int b = blockIdx.x, t = threadIdx.x;             // grid == 16 x 1024
    unsigned cc = ghist[b * 1024 + t];
    ghist[b * 1024 + t] = 0u;                        // ready for next pass
    int U = (int)csize[b];
    if (U <= K_) return;
    __shared__ unsigned s[1024];
    s[t] = cc;
    __syncthreads();
    for (int off = 1; off < 1024; off <<= 1) {       // inclusive suffix sum
        unsigned v = (t + off < 1024) ? s[t + off] : 0u;
        __syncthreads();
        s[t] += v;
        __syncthreads();
    }
    unsigned rem = remg[b];
    unsigned Sincl = s[t];
    unsigned Sexcl = Sincl - cc;                     // sum of bins strictly above t
    if (Sexcl < rem && rem <= Sincl) {               // unique t (requires cc > 0)
        pfx[b] |= ((ull)t) << sh;
        remg[b] = rem - Sexcl;
    }
}

// Collect winners (keys >= threshold; all keys when U<=K) via block-aggregated append.
__global__ void __launch_bounds__(256)
k_collect(const unsigned* __restrict__ csize, const ull* __restrict__ ckeys,
          const ull* __restrict__ pfx, ull* __restrict__ gwin,
          unsigned* __restrict__ gwc) {
    int b, chunk;
    swz(blockIdx.x, b, chunk);                       // grid == 128
    int U = (int)csize[b];
    ull thr = pfx[b];                                // 0 when U<=K -> all pass
    const ull* keys = ckeys + (size_t)b * C_;
    __shared__ unsigned woff[4];
    __shared__ unsigned bbase;
    for (int i0 = chunk * 256; i0 < U; i0 += 2048) {
        int i = i0 + threadIdx.x;
        ull k = 0ull;
        bool valid = false;
        if (i < U) { k = keys[i]; valid = (k >= thr); }
        unsigned long long mask = __ballot(valid);
        int lane = threadIdx.x & 63, wave = threadIdx.x >> 6;
        if (lane == 0) woff[wave] = (unsigned)__popcll(mask);
        __syncthreads();
        if (threadIdx.x == 0) {
            unsigned tot = 0;
            for (int w2 = 0; w2 < 4; ++w2) { unsigned c = woff[w2]; woff[w2] = tot; tot += c; }
            bbase = (tot != 0u) ? atomicAdd(&gwc[b], tot) : 0u;
        }
        __syncthreads();
        if (valid) {
            unsigned pos = bbase + woff[wave]
                         + (unsigned)__popcll(mask & ((1ull << lane) - 1ull));
            gwin[b * K_ + pos] = k;
        }
        __syncthreads();                             // woff/bbase reused next iter
    }
}

// Rank-sort the <=256 winners; write labels into the hash table.
__global__ void __launch_bounds__(256)
k_rank(const unsigned* __restrict__ csize, const unsigned* __restrict__ gwc,
       const ull* __restrict__ gwin, ull* __restrict__ tab) {
    int b = blockIdx.x;                              // batch b -> XCD b%8
    int U = (int)csize[b];
    int S = (int)gwc[b];                             // ==256 when U>K, else ==U
    __shared__ ull sk[K_];
    int t = threadIdx.x;
    if (t < S) sk[t] = gwin[b * K_ + t];
    __syncthreads();
    if (t < S) {
        // U>K: rank by full key desc (count desc, id asc).
        // U<=K: dense rank by id asc == low-32 (~u) desc.
        ull k = sk[t];
        int rank = 0;
        if (U > K_) {
            for (int j = 0; j < S; ++j) rank += (sk[j] > k);
        } else {
            unsigned kl = (unsigned)k;
            for (int j = 0; j < S; ++j) rank += ((unsigned)sk[j] > kl);
        }
        unsigned u = ~((unsigned)k);
        int id = (int)(u ^ 0x80000000u);
        ull* tb = tab + (size_t)b * C_;
        unsigned s = hash_id(id);
        while ((unsigned)(tb[s] >> 32) != u) s = (s + 1) & CMASK_;
        tb[s] = ((ull)u << 32) | (ull)(~(unsigned)rank);
    }
}

__global__ void k_label(const int* __restrict__ pslot, const ull* __restrict__ tab,
                        int* __restrict__ out) {
    int b, chunk;
    swz(blockIdx.x, b, chunk);                       // grid == B_*N_/256
    int p = chunk * 256 + threadIdx.x;
    int i = (b << LOGN_) + p;
    int s = __builtin_nontemporal_load(&pslot[i]);
    ull e = tab[(size_t)b * C_ + s];                 // random gather: table is L2-hot
    unsigned low = (unsigned)e;
    __builtin_nontemporal_store((low >= 0xFFF00000u) ? (int)(~low) : -1, &out[i]);
}

extern "C" void kernel_launch(void* const* d_in, const int* in_sizes, int n_in,
                              void* d_out, int out_size, void* d_ws, size_t ws_size,
                              hipStream_t stream) {
    const float* coords = (const float*)d_in[0];
    int* out = (int*)d_out;

    // Workspace layout (~48 MB + 100 KB):
    char* w = (char*)d_ws;
    size_t off = 0;
    ull* tab = (ull*)(w + off);                 off += (size_t)B_ * C_ * 8;   // 16 MB
    int* pslot = (int*)(w + off);               off += (size_t)B_ * N_ * 4;   // 16 MB
    ull* ckeys = (ull*)(w + off);               off += (size_t)B_ * C_ * 8;   // 16 MB
    ull* pfx = (ull*)(w + off);                 off += B_ * 8;
    ull* gwin = (ull*)(w + off);                off += (size_t)B_ * K_ * 8;   // 32 KB
    unsigned* ghist = (unsigned*)(w + off);     off += (size_t)B_ * 1024 * 4; // 64 KB
    unsigned* csize = (unsigned*)(w + off);     off += B_ * 4;
    unsigned* gwc = (unsigned*)(w + off);       off += B_ * 4;
    unsigned* remg = (unsigned*)(w + off);      off += B_ * 4;
    unsigned* wctr = (unsigned*)(w + off);      off += 128 * 4;  // 8 ctrs, 64B apart

    int blocksBN = B_ * N_ / 256;               // 16384, divisible by 16
    int blocksBC = B_ * C_ / 1024;              // 2048, divisible by 16

    hipMemsetAsync(tab, 0, (size_t)B_ * C_ * 8, stream);
    k_init0<<<B_, 1024, 0, stream>>>(pfx, ghist, csize, gwc, remg, wctr);
    k_build<<<1024, 256, 0, stream>>>(coords, tab, pslot, wctr);
    k_compact<<<blocksBC, 1024, 0, stream>>>(tab, ckeys, csize);
    for (int sh = 40; sh >= 0; sh -= 10) {
        k_hist<<<128, 256, 0, stream>>>(csize, ckeys, pfx, ghist, sh);
        k_pick<<<B_, 1024, 0, stream>>>(csize, ghist, pfx, remg, sh);
    }
    k_collect<<<128, 256, 0, stream>>>(csize, ckeys, pfx, gwin, gwc);
    k_rank<<<B_, 256, 0, stream>>>(csize, gwc, gwin, tab);
    k_label<<<blocksBN, 256, 0, stream>>>(pslot, tab, out);
}

// Round 9
// 148.510 us; speedup vs baseline: 3.3968x; 3.3968x over previous
//
#include <hip/hip_runtime.h>
#include <stdint.h>

// SuperpointGenerator: per-batch voxel id -> count -> top-256 by (count desc, id asc)
// -> labels 0..255 (else -1); if U<=256, label = dense rank by ascending id.
//
// R7/R8 measured: global RMW atomics on gfx950 execute memory-side (~64B fabric
// round trip each, scope-independent). So counting avoids global atomics:
//   - direct-mapped table gtab[64^3] u32 per batch (voxel coords |v|<32; the
//     id hash x*10000+y*100+z is injective there, id reconstructible),
//   - central 28^3 cube (98.5% of N(0,1)/0.2 points) counted in per-block LDS
//     u16-packed histograms, flushed with PLAIN coalesced stores and summed by
//     a merge kernel with plain loads/stores (no atomics at all),
//   - ring 28^3..64^3 (1.5%): direct global atomicAdd (~64K ops total),
//   - outside +-32 (~never, but exact): tiny per-batch CAS hash table otab.
// Labels: winners' table entries overwritten with ~rank (>= 0xFFFFFF00);
// decode low >= 0xFFF00000. Counts <= 2^18 never collide with that range.
// XCD affinity: blocks of batch b have blockIdx%8 == b%8 (L2 locality heuristic).

namespace {
constexpr int B_ = 16;
constexpr int N_ = 262144;            // 2^18 points per batch
constexpr int LOGN_ = 18;
constexpr int K_ = 256;
constexpr int G_ = 262144;            // 64^3 direct slots per batch
constexpr int OC_ = 4096;             // overflow CAS slots per batch
constexpr int CKSTR_ = G_ + OC_;      // ckeys stride per batch
constexpr int DIM_ = 28, HDIM_ = 14;  // central LDS cube: voxels [-14,14)
constexpr int BINS_ = DIM_ * DIM_ * DIM_;   // 21952
constexpr int WORDS_ = BINS_ / 2;           // 10976 packed u32 words
constexpr int BPB_ = 32;              // build blocks per batch
constexpr int PPB_ = N_ / BPB_;       // 8192 points per build block
typedef unsigned long long ull;
}

// bid -> (batch, chunk): batch = (bid&7) + 8*((bid>>3)&1)  => batch % 8 == bid % 8
__device__ __forceinline__ void swz(int bid, int& b, int& chunk) {
    b = (bid & 7) + (((bid >> 3) & 1) << 3);
    chunk = bid >> 4;
}

__device__ __forceinline__ unsigned ohash(int id) {
    return ((unsigned)id * 2654435761u) >> 20;       // 12-bit slot in otab
}

// Block-aggregated append of valid keys to ckeys[b] (one global atomic / block).
__device__ __forceinline__ void append_keys(bool valid, ull key, int b,
                                            ull* __restrict__ ckeys,
                                            unsigned* __restrict__ csize,
                                            unsigned* woff, unsigned* pbase) {
    ull mask = __ballot(valid);
    int lane = threadIdx.x & 63, wave = threadIdx.x >> 6;
    if (lane == 0) woff[wave] = (unsigned)__popcll(mask);
    __syncthreads();
    if (threadIdx.x == 0) {
        int nw = blockDim.x >> 6;
        unsigned tot = 0;
        for (int w2 = 0; w2 < nw; ++w2) { unsigned c = woff[w2]; woff[w2] = tot; tot += c; }
        *pbase = tot ? atomicAdd(&csize[b], tot) : 0u;
    }
    __syncthreads();
    if (valid) {
        unsigned pos = *pbase + woff[wave]
                     + (unsigned)__popcll(mask & ((1ull << lane) - 1ull));
        ckeys[(size_t)b * CKSTR_ + pos] = key;
    }
}

__global__ void __launch_bounds__(1024)
k_build(const float* __restrict__ coords, unsigned* __restrict__ gtab,
        ull* __restrict__ otab, int* __restrict__ pslot,
        unsigned* __restrict__ phist) {
    int b, chunk;
    swz(blockIdx.x, b, chunk);                       // grid == 512 (16 x 32)
    __shared__ unsigned lh[WORDS_];                  // 43.9 KB packed u16 pairs
    for (int w = threadIdx.x; w < WORDS_; w += 1024) lh[w] = 0u;
    __syncthreads();
    for (int r = 0; r < PPB_ / 1024; ++r) {
        int p = chunk * PPB_ + r * 1024 + (int)threadIdx.x;
        size_t i = ((size_t)b << LOGN_) + (size_t)p;
        const float* c = coords + i * 3;
        // Must match jnp.floor(c / 0.2f) bit-exactly: IEEE fp32 division.
        float cx = __builtin_nontemporal_load(c + 0);
        float cy = __builtin_nontemporal_load(c + 1);
        float cz = __builtin_nontemporal_load(c + 2);
        int vx = (int)floorf(cx / 0.2f);
        int vy = (int)floorf(cy / 0.2f);
        int vz = (int)floorf(cz / 0.2f);
        int ax = vx + HDIM_, ay = vy + HDIM_, az = vz + HDIM_;
        if ((unsigned)ax < (unsigned)DIM_ && (unsigned)ay < (unsigned)DIM_ &&
            (unsigned)az < (unsigned)DIM_) {
            int lidx = (ax * DIM_ + ay) * DIM_ + az;
            atomicAdd(&lh[lidx >> 1], 1u << ((lidx & 1) << 4));   // LDS, packed u16
            int gidx = ((vx + 32) << 12) | ((vy + 32) << 6) | (vz + 32);
            __builtin_nontemporal_store(gidx, &pslot[i]);
        } else if ((unsigned)(vx + 32) < 64u && (unsigned)(vy + 32) < 64u &&
                   (unsigned)(vz + 32) < 64u) {
            int gidx = ((vx + 32) << 12) | ((vy + 32) << 6) | (vz + 32);
            atomicAdd(&gtab[((size_t)b << 18) | gidx], 1u);       // ~1.5% of points
            __builtin_nontemporal_store(gidx, &pslot[i]);
        } else {                                     // essentially never; exact
            int id = vx * 10000 + vy * 100 + vz;
            unsigned u = (unsigned)id ^ 0x80000000u;
            unsigned s = ohash(id);
            ull* t = otab + (size_t)b * OC_;
            for (;;) {
                ull cur = t[s];
                if (cur == 0ull) {
                    ull prev = atomicCAS(&t[s], 0ull, ((ull)u << 32) | 1ull);
                    if (prev == 0ull) break;
                    cur = prev;
                }
                if ((unsigned)(cur >> 32) == u) { atomicAdd(&t[s], 1ull); break; }
                s = (s + 1) & (OC_ - 1);
            }
            __builtin_nontemporal_store((int)(0x80000000u | s), &pslot[i]);
        }
    }
    __syncthreads();
    unsigned* ph = phist + (size_t)(b * BPB_ + chunk) * WORDS_;
    for (int w = threadIdx.x; w < WORDS_; w += 1024)
        __builtin_nontemporal_store(lh[w], &ph[w]);  // plain coalesced flush
}

// Sum the 32 private histograms per batch into the direct table (plain mem ops).
__global__ void __launch_bounds__(256)
k_merge(const unsigned* __restrict__ phist, unsigned* __restrict__ gtab) {
    int b, chunk;
    swz(blockIdx.x, b, chunk);                       // grid == 688 (16 x 43)
    int w = chunk * 256 + (int)threadIdx.x;
    if (w >= WORDS_) return;
    unsigned s0 = 0, s1 = 0;
    const unsigned* ph = phist + (size_t)b * BPB_ * WORDS_ + w;
    for (int blk = 0; blk < BPB_; ++blk) {
        unsigned v = __builtin_nontemporal_load(ph + (size_t)blk * WORDS_);
        s0 += v & 0xFFFFu;
        s1 += v >> 16;
    }
    int bin0 = 2 * w;                                // pair (az, az+1), az even
    int ax = bin0 / (DIM_ * DIM_);
    int r2 = bin0 % (DIM_ * DIM_);
    int ay = r2 / DIM_, az = r2 % DIM_;
    int gidx = ((ax - HDIM_ + 32) << 12) | ((ay - HDIM_ + 32) << 6) | (az - HDIM_ + 32);
    *(ull*)&gtab[((size_t)b << 18) | gidx] = (ull)s0 | ((ull)s1 << 32);  // 8B aligned
}

// Compact nonzero voxels into per-batch priority-key arrays.
// chunks 0..255: gtab scan (id reconstructed from gidx). chunk 256: otab scan.
__global__ void __launch_bounds__(1024)
k_compact(const unsigned* __restrict__ gtab, const ull* __restrict__ otab,
          ull* __restrict__ ckeys, unsigned* __restrict__ csize) {
    int b, chunk;
    swz(blockIdx.x, b, chunk);                       // grid == 4112 (16 x 257)
    __shared__ unsigned woff[16];
    __shared__ unsigned pbase;
    if (chunk < 256) {
        int f = chunk * 1024 + (int)threadIdx.x;     // [0, 2^18)
        unsigned cnt = gtab[((size_t)b << 18) | f];
        bool valid = (cnt != 0u);
        ull key = 0ull;
        if (valid) {
            int vx = (f >> 12) - 32, vy = ((f >> 6) & 63) - 32, vz = (f & 63) - 32;
            int id = vx * 10000 + vy * 100 + vz;
            unsigned u = (unsigned)id ^ 0x80000000u;
            key = ((ull)cnt << 32) | (ull)(~u);      // (count desc, id asc)
        }
        append_keys(valid, key, b, ckeys, csize, woff, &pbase);
    } else {
        for (int it = 0; it < OC_ / 1024; ++it) {
            ull e = otab[(size_t)b * OC_ + it * 1024 + threadIdx.x];
            bool valid = (e != 0ull);
            ull key = ((ull)(unsigned)e << 32) | (ull)(~(unsigned)(e >> 32));
            append_keys(valid, key, b, ckeys, csize, woff, &pbase);
            __syncthreads();
        }
    }
}

// One radix pass histogram (10-bit digit at shift sh; 5 passes cover 50-bit keys).
__global__ void __launch_bounds__(256)
k_hist(const unsigned* __restrict__ csize, const ull* __restrict__ ckeys,
       const ull* __restrict__ pfx, unsigned* __restrict__ ghist, int sh) {
    int b, chunk;
    swz(blockIdx.x, b, chunk);                       // grid == 128 (16 x 8)
    int U = (int)csize[b];
    if (U <= K_) return;
    ull prefix = (sh == 40) ? 0ull : pfx[b];
    ull hi = ~0ull << (sh + 10);
    __shared__ unsigned lhh[1024];
    for (int d = threadIdx.x; d < 1024; d += 256) lhh[d] = 0u;
    __syncthreads();
    const ull* keys = ckeys + (size_t)b * CKSTR_;
    for (int i = chunk * 256 + (int)threadIdx.x; i < U; i += 2048) {
        ull k = keys[i];
        if ((k & hi) == prefix)
            atomicAdd(&lhh[(unsigned)(k >> sh) & 1023u], 1u);
    }
    __syncthreads();
    for (int d = threadIdx.x; d < 1024; d += 256) {
        unsigned c = lhh[d];
        if (c) atomicAdd(&ghist[b * 1024 + d], c);
    }
}

// Pick the digit bin holding the rem-th largest; update prefix/rem; re-zero ghist.
__global__ void __launch_bounds__(1024)
k_pick(const unsigned* __restrict__ csize, unsigned* __restrict__ ghist,
       ull* __restrict__ pfx, unsigned* __restrict__ remg, int sh) {
    int b = blockIdx.x, t = threadIdx.x;             // grid == 16 x 1024
    unsigned cc = ghist[b * 1024 + t];
    ghist[b * 1024 + t] = 0u;
    int U = (int)csize[b];
    if (U <= K_) return;
    __shared__ unsigned s[1024];
    s[t] = cc;
    __syncthreads();
    for (int off = 1; off < 1024; off <<= 1) {       // inclusive suffix sum
        unsigned v = (t + off < 1024) ? s[t + off] : 0u;
        __syncthreads();
        s[t] += v;
        __syncthreads();
    }
    unsigned rem = (sh == 40) ? (unsigned)K_ : remg[b];
    unsigned Sincl = s[t];
    unsigned Sexcl = Sincl - cc;
    if (Sexcl < rem && rem <= Sincl) {               // unique t
        pfx[b] = ((sh == 40) ? 0ull : pfx[b]) | ((ull)t << sh);
        remg[b] = rem - Sexcl;
    }
}

// Collect winners (keys >= threshold; all keys when U<=K).
__global__ void __launch_bounds__(256)
k_collect(const unsigned* __restrict__ csize, const ull* __restrict__ ckeys,
          const ull* __restrict__ pfx, ull* __restrict__ gwin,
          unsigned* __restrict__ gwc) {
    int b, chunk;
    swz(blockIdx.x, b, chunk);                       // grid == 128
    int U = (int)csize[b];
    ull thr = (U <= K_) ? 0ull : pfx[b];
    const ull* keys = ckeys + (size_t)b * CKSTR_;
    __shared__ unsigned woff[4];
    __shared__ unsigned bbase;
    for (int i0 = chunk * 256; i0 < U; i0 += 2048) {
        int i = i0 + (int)threadIdx.x;
        ull k = 0ull;
        bool valid = false;
        if (i < U) { k = keys[i]; valid = (k >= thr); }
        ull mask = __ballot(valid);
        int lane = threadIdx.x & 63, wave = threadIdx.x >> 6;
        if (lane == 0) woff[wave] = (unsigned)__popcll(mask);
        __syncthreads();
        if (threadIdx.x == 0) {
            unsigned tot = 0;
            for (int w2 = 0; w2 < 4; ++w2) { unsigned c = woff[w2]; woff[w2] = tot; tot += c; }
            bbase = tot ? atomicAdd(&gwc[b], tot) : 0u;
        }
        __syncthreads();
        if (valid) {
            unsigned pos = bbase + woff[wave]
                         + (unsigned)__popcll(mask & ((1ull << lane) - 1ull));
            gwin[b * K_ + pos] = k;
        }
        __syncthreads();
    }
}

// Rank-sort the <=256 winners; write ~rank into gtab (or otab for overflow ids).
__global__ void __launch_bounds__(256)
k_rank(const unsigned* __restrict__ csize, const unsigned* __restrict__ gwc,
       const ull* __restrict__ gwin, unsigned* __restrict__ gtab,
       ull* __restrict__ otab) {
    int b = blockIdx.x;
    int U = (int)csize[b];
    int S = (int)gwc[b];                             // ==256 when U>K, else ==U
    __shared__ ull sk[K_];
    int t = threadIdx.x;
    if (t < S) sk[t] = gwin[b * K_ + t];
    __syncthreads();
    if (t < S) {
        ull k = sk[t];
        int rank = 0;
        if (U > K_) {
            for (int j = 0; j < S; ++j) rank += (sk[j] > k);       // full key desc
        } else {
            unsigned kl = (unsigned)k;
            for (int j = 0; j < S; ++j) rank += ((unsigned)sk[j] > kl);  // id asc
        }
        unsigned u = ~((unsigned)k);
        int id = (int)(u ^ 0x80000000u);
        int idp = id + 32 * 10000 + 32 * 100 + 32;   // (vx+32)*1e4+(vy+32)*1e2+(vz+32)
        bool direct = false; int gidx = 0;
        if (idp >= 0) {
            int a = idp / 10000, r2 = idp % 10000, bb = r2 / 100, cc = r2 % 100;
            if (a < 64 && bb < 64 && cc < 64) { direct = true; gidx = (a << 12) | (bb << 6) | cc; }
        }
        if (direct) {
            gtab[((size_t)b << 18) | gidx] = ~(unsigned)rank;
        } else {
            unsigned s2 = ohash(id);
            ull* tb = otab + (size_t)b * OC_;
            while ((unsigned)(tb[s2] >> 32) != u) s2 = (s2 + 1) & (OC_ - 1);
            tb[s2] = ((ull)u << 32) | (ull)(~(unsigned)rank);
        }
    }
}

__global__ void k_label(const int* __restrict__ pslot, const unsigned* __restrict__ gtab,
                        const ull* __restrict__ otab, int* __restrict__ out) {
    int b, chunk;
    swz(blockIdx.x, b, chunk);                       // grid == B_*N_/256
    int p = chunk * 256 + (int)threadIdx.x;
    size_t i = ((size_t)b << LOGN_) + (size_t)p;
    int s = __builtin_nontemporal_load(&pslot[i]);
    unsigned low;
    if (s >= 0) low = gtab[((size_t)b << 18) | s];
    else        low = (unsigned)otab[(size_t)b * OC_ + (s & (OC_ - 1))];
    __builtin_nontemporal_store((low >= 0xFFF00000u) ? (int)(~low) : -1, &out[i]);
}

extern "C" void kernel_launch(void* const* d_in, const int* in_sizes, int n_in,
                              void* d_out, int out_size, void* d_ws, size_t ws_size,
                              hipStream_t stream) {
    const float* coords = (const float*)d_in[0];
    int* out = (int*)d_out;

    // Workspace layout (~65 MB):
    char* w = (char*)d_ws;
    size_t off = 0;
    unsigned* gtab = (unsigned*)(w + off);      off += (size_t)B_ * G_ * 4;   // 16 MB
    ull* otab = (ull*)(w + off);                off += (size_t)B_ * OC_ * 8;  // 512 KB (contiguous after gtab)
    int* pslot = (int*)(w + off);               off += (size_t)B_ * N_ * 4;   // 16 MB
    char* unionreg = w + off;                   off += (size_t)B_ * CKSTR_ * 8; // 32.5 MB
    unsigned* phist = (unsigned*)unionreg;      // live: build -> merge (22.5 MB)
    ull* ckeys = (ull*)unionreg;                // live: compact -> collect
    unsigned* ghist = (unsigned*)(w + off);     off += (size_t)B_ * 1024 * 4; // 64 KB
    unsigned* csize = (unsigned*)(w + off);     off += B_ * 4;
    unsigned* gwc = (unsigned*)(w + off);       off += B_ * 4;                // (ghist..gwc contiguous)
    ull* pfx = (ull*)(w + off);                 off += B_ * 8;
    unsigned* remg = (unsigned*)(w + off);      off += B_ * 4;
    ull* gwin = (ull*)(w + off);                off += (size_t)B_ * K_ * 8;   // 32 KB

    hipMemsetAsync(gtab, 0, (size_t)B_ * G_ * 4 + (size_t)B_ * OC_ * 8, stream);
    hipMemsetAsync(ghist, 0, (size_t)B_ * 1024 * 4 + 2 * B_ * 4, stream);

    k_build<<<B_ * BPB_, 1024, 0, stream>>>(coords, gtab, otab, pslot, phist);
    k_merge<<<16 * ((WORDS_ + 255) / 256), 256, 0, stream>>>(phist, gtab);
    k_compact<<<16 * 257, 1024, 0, stream>>>(gtab, otab, ckeys, csize);
    for (int sh = 40; sh >= 0; sh -= 10) {
        k_hist<<<128, 256, 0, stream>>>(csize, ckeys, pfx, ghist, sh);
        k_pick<<<B_, 1024, 0, stream>>>(csize, ghist, pfx, remg, sh);
    }
    k_collect<<<128, 256, 0, stream>>>(csize, ckeys, pfx, gwin, gwc);
    k_rank<<<B_, 256, 0, stream>>>(csize, gwc, gwin, gtab, otab);
    k_label<<<B_ * N_ / 256, 256, 0, stream>>>(pslot, gtab, otab, out);
}